// Round 1
// baseline (643.777 us; speedup 1.0000x reference)
//
#include <hip/hip_runtime.h>

// NeighborAttention fused kernel for MI355X (gfx950).
// B=4,N=2000,K=30,H=128,HEADS=4,D=32,NUM_IN=256. All inputs fp32, output fp32.
// Strategy: 1 block = 2 tokens. Stage fp32->bf16 neighbor tiles into LDS,
// bf16 MFMA 16x16x32 projections (weights pre-cast to bf16 in ws),
// fp32 logits/softmax/aggregation, fp32 output GEMM. HBM-bound target ~80us.

#define BB 4
#define NNTOK 2000
#define KNB 30
#define HH 128
#define NHEADS 4
#define DDIM 32
#define NUMIN 256
#define TOK (BB*NNTOK)      // 8000
#define TB 2                // tokens per block
#define NBLK (TOK/TB)       // 4000
#define SAW 136             // LDS row stride in bf16 elems (128 + 8 pad, keeps 16B align)

typedef __bf16 bf16x8 __attribute__((ext_vector_type(8)));
typedef __bf16 bf16x4_t __attribute__((ext_vector_type(4)));
typedef float f32x4 __attribute__((ext_vector_type(4)));

// ws layout (bf16): [W_K1 16384][W_K2 16384][W_V 32768]  = 131072 bytes
__global__ __launch_bounds__(256) void conv_w_kernel(
    const float* __restrict__ wk1, const float* __restrict__ wk2,
    const float* __restrict__ wv, __bf16* __restrict__ ws) {
  int i = blockIdx.x * 256 + threadIdx.x;   // quad index, 16384 total
  int e = i * 4;
  const float* src;
  int off;
  if (e < 16384)      { src = wk1; off = e; }
  else if (e < 32768) { src = wk2; off = e - 16384; }
  else                { src = wv;  off = e - 32768; }
  float4 v = *(const float4*)(src + off);
  bf16x4_t o4;
  o4.x = (__bf16)v.x; o4.y = (__bf16)v.y; o4.z = (__bf16)v.z; o4.w = (__bf16)v.w;
  *(bf16x4_t*)(ws + e) = o4;
}

__global__ __launch_bounds__(256, 4) void na_main_kernel(
    const float* __restrict__ h_V, const float* __restrict__ h_EV,
    const float* __restrict__ h_KV, const float* __restrict__ h_KE,
    const float* __restrict__ maskp, const float* __restrict__ W_Q,
    const float* __restrict__ W_O, const __bf16* __restrict__ bW,
    float* __restrict__ out) {
  __shared__ __bf16 sA[64 * SAW];     // staged A tile (bf16), 17408 B
  __shared__ __bf16 sKP[64 * SAW];    // K1 -> P=K1*K2 -> V           17408 B
  __shared__ float sQ[TB][HH];        // Q, later reused as h_upd
  __shared__ float sLog[TB][NHEADS][32]; // logits -> attend (in place)
  __shared__ float sMask[TB][32];

  const int tid = threadIdx.x;
  const int lane = tid & 63;
  const int wave = tid >> 6;
  const int m = lane & 15;
  const int quad = lane >> 4;
  const int t0 = blockIdx.x * TB;

  const __bf16* bWK1 = bW;
  const __bf16* bWK2 = bW + 16384;
  const __bf16* bWV  = bW + 32768;

  // ---- phase 0: mask load, zero pad rows 60..63 of sA, Q projection ----
  for (int i = tid; i < TB * KNB; i += 256)
    sMask[i / KNB][i % KNB] = maskp[(long)(t0 + i / KNB) * KNB + i % KNB];
  for (int i = tid; i < 4 * SAW; i += 256)
    sA[60 * SAW + i] = (__bf16)0.f;
  {
    const int t = tid >> 7, o = tid & 127;
    const float4* wq = (const float4*)(W_Q + o * HH);
    const float4* hv = (const float4*)(h_V + (long)(t0 + t) * HH);
    float acc = 0.f;
#pragma unroll
    for (int j = 0; j < 32; j++) {
      float4 a = hv[j], b = wq[j];
      acc += a.x * b.x + a.y * b.y + a.z * b.z + a.w * b.w;
    }
    sQ[t][o] = acc;
  }

  // staging helper: 60 rows x 128 fp32 cols -> bf16 LDS (stride SAW)
  auto stage = [&](const float* gsrc, int grs) {
    for (int i = tid; i < 60 * 32; i += 256) {
      int r = i >> 5, c = (i & 31) << 2;
      float4 v = *(const float4*)(gsrc + (long)r * grs + c);
      bf16x4_t o4;
      o4.x = (__bf16)v.x; o4.y = (__bf16)v.y; o4.z = (__bf16)v.z; o4.w = (__bf16)v.w;
      *(bf16x4_t*)&sA[r * SAW + c] = o4;
    }
  };

  f32x4 acc[4][2];
  const f32x4 fzero = {0.f, 0.f, 0.f, 0.f};
  auto zacc = [&]() {
#pragma unroll
    for (int mt = 0; mt < 4; mt++) { acc[mt][0] = fzero; acc[mt][1] = fzero; }
  };
  // one wave handles cols [wave*32, wave*32+32), all 4 M-tiles, 4 k-steps
  auto gemm = [&](const __bf16* gW, int ldw, int kb) {
#pragma unroll
    for (int ks = 0; ks < 4; ks++) {
      const int kc = kb + ks * 32 + quad * 8;
      bf16x8 b0 = *(const bf16x8*)(gW + (wave * 32 + m) * ldw + kc);
      bf16x8 b1 = *(const bf16x8*)(gW + (wave * 32 + 16 + m) * ldw + kc);
#pragma unroll
      for (int mt = 0; mt < 4; mt++) {
        bf16x8 a = *(const bf16x8*)&sA[(mt * 16 + m) * SAW + ks * 32 + quad * 8];
        acc[mt][0] = __builtin_amdgcn_mfma_f32_16x16x32_bf16(a, b0, acc[mt][0], 0, 0, 0);
        acc[mt][1] = __builtin_amdgcn_mfma_f32_16x16x32_bf16(a, b1, acc[mt][1], 0, 0, 0);
      }
    }
  };

  __syncthreads();

  // ---- K1 = KE @ W_K1^T ----
  stage(h_KE + (long)t0 * KNB * HH, HH);
  __syncthreads();
  zacc();
  gemm(bWK1, HH, 0);
#pragma unroll
  for (int mt = 0; mt < 4; mt++)
#pragma unroll
    for (int nt = 0; nt < 2; nt++)
#pragma unroll
      for (int r = 0; r < 4; r++)
        sKP[(mt * 16 + quad * 4 + r) * SAW + wave * 32 + nt * 16 + m] =
            (__bf16)acc[mt][nt][r];
  __syncthreads();

  // ---- K2 = KV @ W_K2^T, P = K1*K2 in place ----
  stage(h_KV + (long)t0 * KNB * HH, HH);
  __syncthreads();
  zacc();
  gemm(bWK2, HH, 0);
#pragma unroll
  for (int mt = 0; mt < 4; mt++)
#pragma unroll
    for (int nt = 0; nt < 2; nt++)
#pragma unroll
      for (int r = 0; r < 4; r++) {
        int idx = (mt * 16 + quad * 4 + r) * SAW + wave * 32 + nt * 16 + m;
        sKP[idx] = (__bf16)((float)sKP[idx] * acc[mt][nt][r]);
      }
  __syncthreads();

  // ---- logits: sum_d Q * P / 32 ----
  if (tid < TB * NHEADS * KNB) {
    int t = tid / (NHEADS * KNB), rem = tid % (NHEADS * KNB);
    int h = rem / KNB, k = rem % KNB;
    const __bf16* p = &sKP[(t * KNB + k) * SAW + h * DDIM];
    const float* q = &sQ[t][h * DDIM];
    float s = 0.f;
#pragma unroll
    for (int d = 0; d < DDIM; d++) s += q[d] * (float)p[d];
    sLog[t][h][k] = s * (1.f / DDIM);
  }
  __syncthreads();

  // ---- masked softmax over k, attend stored in place ----
  if (tid < TB * NHEADS) {
    int t = tid >> 2, h = tid & 3;
    float mx = -3.4e38f;
    for (int k = 0; k < KNB; k++)
      if (sMask[t][k] > 0.f) mx = fmaxf(mx, sLog[t][h][k]);
    float s = 0.f;
    for (int k = 0; k < KNB; k++) {
      float e = (sMask[t][k] > 0.f) ? __expf(sLog[t][h][k] - mx) : 0.f;
      sLog[t][h][k] = e;
      s += e;
    }
    float inv = (s > 0.f) ? 1.f / s : 0.f;
    for (int k = 0; k < KNB; k++) sLog[t][h][k] *= inv;
  }
  __syncthreads();

  // ---- V = EV @ W_V^T (K=256, two staged halves) ----
  zacc();
  stage(h_EV + (long)t0 * KNB * NUMIN, NUMIN);
  __syncthreads();
  gemm(bWV, NUMIN, 0);
  __syncthreads();
  stage(h_EV + (long)t0 * KNB * NUMIN + 128, NUMIN);
  __syncthreads();
  gemm(bWV, NUMIN, 128);
#pragma unroll
  for (int mt = 0; mt < 4; mt++)
#pragma unroll
    for (int nt = 0; nt < 2; nt++)
#pragma unroll
      for (int r = 0; r < 4; r++)
        sKP[(mt * 16 + quad * 4 + r) * SAW + wave * 32 + nt * 16 + m] =
            (__bf16)acc[mt][nt][r];
  __syncthreads();

  // ---- aggregation: h_upd[t,c] = sum_k attend[t,h(c),k] * V[t*30+k, c] ----
  {
    const int t = tid >> 7, c = tid & 127, h = c >> 5;
    float a = 0.f;
#pragma unroll
    for (int k = 0; k < KNB; k++)
      a += sLog[t][h][k] * (float)sKP[(t * KNB + k) * SAW + c];
    sQ[t][c] = a;  // sQ no longer needed as Q
  }
  __syncthreads();

  // ---- out = h_upd @ W_O^T (fp32) ----
  {
    const int t = tid >> 7, o = tid & 127;
    const float4* wo = (const float4*)(W_O + o * HH);
    const float4* u = (const float4*)&sQ[t][0];
    float r = 0.f;
#pragma unroll
    for (int j = 0; j < 32; j++) {
      float4 a = u[j], b = wo[j];
      r += a.x * b.x + a.y * b.y + a.z * b.z + a.w * b.w;
    }
    out[(long)(t0 + t) * HH + o] = r;
  }
}

extern "C" void kernel_launch(void* const* d_in, const int* in_sizes, int n_in,
                              void* d_out, int out_size, void* d_ws, size_t ws_size,
                              hipStream_t stream) {
  const float* h_V  = (const float*)d_in[0];
  const float* h_EV = (const float*)d_in[1];
  const float* h_KV = (const float*)d_in[2];
  const float* h_KE = (const float*)d_in[3];
  const float* mask = (const float*)d_in[4];
  const float* W_Q  = (const float*)d_in[5];
  const float* W_K1 = (const float*)d_in[6];
  const float* W_K2 = (const float*)d_in[7];
  const float* W_V  = (const float*)d_in[8];
  const float* W_O  = (const float*)d_in[9];
  __bf16* bW = (__bf16*)d_ws;  // 131072 bytes of bf16 weights

  conv_w_kernel<<<64, 256, 0, stream>>>(W_K1, W_K2, W_V, bW);
  na_main_kernel<<<NBLK, 256, 0, stream>>>(h_V, h_EV, h_KV, h_KE, mask,
                                           W_Q, W_O, bW, (float*)d_out);
}

// Round 2
// 628.244 us; speedup vs baseline: 1.0247x; 1.0247x over previous
//
#include <hip/hip_runtime.h>

// NeighborAttention fused, round 2: register-resident P/attend/V, wave-local
// softmax, double-buffered LDS staging with register prefetch. B=4,N=2000,
// K=30,H=128,HEADS=4,D=32,NUM_IN=256. fp32 in/out, bf16 MFMA compute.

#define KNB 30
#define HH 128
#define NUMIN 256
#define TOK 8000
#define TOTROW (TOK*KNB)    // 240000
#define TB 2
#define NBLK (TOK/TB)       // 4000
#define SAW 136             // LDS row stride (bf16 elems): 128 + 8 pad

typedef __bf16 bf16x8 __attribute__((ext_vector_type(8)));
typedef __bf16 bf16x4_t __attribute__((ext_vector_type(4)));
typedef float f32x4 __attribute__((ext_vector_type(4)));

// ws layout (bf16): [W_K1 16384][W_K2 16384][W_V 32768]
__global__ __launch_bounds__(256) void conv_w_kernel(
    const float* __restrict__ wk1, const float* __restrict__ wk2,
    const float* __restrict__ wv, __bf16* __restrict__ ws) {
  int e = (blockIdx.x * 256 + threadIdx.x) * 4;
  const float* src; int off;
  if (e < 16384)      { src = wk1; off = e; }
  else if (e < 32768) { src = wk2; off = e - 16384; }
  else                { src = wv;  off = e - 32768; }
  float4 v = *(const float4*)(src + off);
  bf16x4_t o4;
  o4.x = (__bf16)v.x; o4.y = (__bf16)v.y; o4.z = (__bf16)v.z; o4.w = (__bf16)v.w;
  *(bf16x4_t*)(ws + e) = o4;
}

__global__ __launch_bounds__(256, 4) void na_main_kernel(
    const float* __restrict__ h_V, const float* __restrict__ h_EV,
    const float* __restrict__ h_KV, const float* __restrict__ h_KE,
    const float* __restrict__ maskp, const float* __restrict__ W_Q,
    const float* __restrict__ W_O, const __bf16* __restrict__ bW,
    float* __restrict__ out) {
  __shared__ __bf16 sA[2][64 * SAW];   // double-buffered staging, 2x17408 B
  __shared__ float sQ[TB][HH];
  __shared__ float sU[TB][HH];
  __shared__ float sMask[TB][32];

  const int tid = threadIdx.x;
  const int lane = tid & 63;
  const int wave = tid >> 6;           // wave == head
  const int m = lane & 15;
  const int quad = lane >> 4;
  const int t0 = blockIdx.x * TB;

  const __bf16* bWK1 = bW;
  const __bf16* bWK2 = bW + 16384;
  const __bf16* bWV  = bW + 32768;

  // ---- staging: 64 rows x 128 cols fp32 -> bf16 LDS; 8 float4 per thread ----
  const int srow = tid >> 5;           // 0..7
  const int scol = (tid & 31) << 2;    // 0..124
  float4 sv[8];
  const long r0 = (long)t0 * KNB + srow;

  auto stage_load = [&](const float* base, int ld, int coloff) {
#pragma unroll
    for (int j = 0; j < 8; j++) {
      long rr = r0 + j * 8;
      if (rr > TOTROW - 1) rr = TOTROW - 1;   // clamp (last block rows 60..63)
      sv[j] = *(const float4*)(base + rr * ld + coloff + scol);
    }
  };
  auto stage_store = [&](int b) {
#pragma unroll
    for (int j = 0; j < 8; j++) {
      bf16x4_t o;
      o.x = (__bf16)sv[j].x; o.y = (__bf16)sv[j].y;
      o.z = (__bf16)sv[j].z; o.w = (__bf16)sv[j].w;
      *(bf16x4_t*)&sA[b][(srow + j * 8) * SAW + scol] = o;
    }
  };

  f32x4 accA[4][2], accB[4][2];
  const f32x4 fzero = {0.f, 0.f, 0.f, 0.f};
  // one wave: cols [wave*32, wave*32+32), 4 M-tiles, 4 k-steps into given acc
  auto gemm = [&](const __bf16* gW, int ldw, int kb, const __bf16* Ab,
                  f32x4 (*acc)[2]) {
#pragma unroll
    for (int ks = 0; ks < 4; ks++) {
      const int kc = kb + ks * 32 + quad * 8;
      bf16x8 b0 = *(const bf16x8*)(gW + (wave * 32 + m) * ldw + kc);
      bf16x8 b1 = *(const bf16x8*)(gW + (wave * 32 + 16 + m) * ldw + kc);
#pragma unroll
      for (int mt = 0; mt < 4; mt++) {
        bf16x8 a = *(const bf16x8*)&Ab[(mt * 16 + m) * SAW + ks * 32 + quad * 8];
        acc[mt][0] = __builtin_amdgcn_mfma_f32_16x16x32_bf16(a, b0, acc[mt][0], 0, 0, 0);
        acc[mt][1] = __builtin_amdgcn_mfma_f32_16x16x32_bf16(a, b1, acc[mt][1], 0, 0, 0);
      }
    }
  };

  // ---- phase 0: KE loads in flight; mask + Q projection under the latency ----
  stage_load(h_KE, HH, 0);
  if (tid < TB * KNB)
    sMask[tid / KNB][tid % KNB] = maskp[(long)t0 * KNB + tid];
  {
    const int t = tid >> 7, o = tid & 127;
    const float4* wq = (const float4*)(W_Q + o * HH);
    const float4* hv = (const float4*)(h_V + (long)(t0 + t) * HH);
    float acc = 0.f;
#pragma unroll
    for (int j = 0; j < 32; j++) {
      float4 a = hv[j], b = wq[j];
      acc += a.x * b.x + a.y * b.y + a.z * b.z + a.w * b.w;
    }
    sQ[t][o] = acc;
  }
  stage_store(0);
  __syncthreads();

  // ---- K1 gemm (buf0) with KV prefetch ----
  stage_load(h_KV, HH, 0);
#pragma unroll
  for (int mt = 0; mt < 4; mt++) { accA[mt][0] = fzero; accA[mt][1] = fzero; }
  gemm(bWK1, HH, 0, sA[0], accA);
  stage_store(1);
  __syncthreads();

  // ---- K2 gemm (buf1); P = K1*K2 in registers ----
#pragma unroll
  for (int mt = 0; mt < 4; mt++) { accB[mt][0] = fzero; accB[mt][1] = fzero; }
  gemm(bWK2, HH, 0, sA[1], accB);
#pragma unroll
  for (int mt = 0; mt < 4; mt++) {
    accA[mt][0] *= accB[mt][0];
    accA[mt][1] *= accB[mt][1];
  }

  // EV-lo loads in flight while we do wave-local logits/softmax
  stage_load(h_EV, NUMIN, 0);

  // ---- logits[t, h=wave, k]: in-wave reduction over d (cols) ----
  float q0[2], q1[2];
#pragma unroll
  for (int nt = 0; nt < 2; nt++) {
    q0[nt] = sQ[0][wave * 32 + nt * 16 + m];
    q1[nt] = sQ[1][wave * 32 + nt * 16 + m];
  }
  float lg[4][4];
#pragma unroll
  for (int mt = 0; mt < 4; mt++)
#pragma unroll
    for (int r = 0; r < 4; r++) {
      int R = mt * 16 + quad * 4 + r;
      float qa0 = (R < 30) ? q0[0] : q1[0];
      float qa1 = (R < 30) ? q0[1] : q1[1];
      lg[mt][r] = accA[mt][0][r] * qa0 + accA[mt][1][r] * qa1;
    }
#pragma unroll
  for (int d = 1; d < 16; d <<= 1)
#pragma unroll
    for (int mt = 0; mt < 4; mt++)
#pragma unroll
      for (int r = 0; r < 4; r++)
        lg[mt][r] += __shfl_xor(lg[mt][r], d);

  // ---- masked softmax (wave-local, quad-reduce) ----
  float mx0 = -3.0e38f, mx1 = -3.0e38f;
#pragma unroll
  for (int mt = 0; mt < 4; mt++)
#pragma unroll
    for (int r = 0; r < 4; r++) {
      int R = mt * 16 + quad * 4 + r;
      if (R < 60) {
        int t = R >= 30, k = R - 30 * t;
        float l = (sMask[t][k] > 0.f) ? lg[mt][r] * 0.03125f : -3.0e38f;
        lg[mt][r] = l;
        if (t == 0) mx0 = fmaxf(mx0, l); else mx1 = fmaxf(mx1, l);
      } else lg[mt][r] = -3.0e38f;
    }
  mx0 = fmaxf(mx0, __shfl_xor(mx0, 16)); mx0 = fmaxf(mx0, __shfl_xor(mx0, 32));
  mx1 = fmaxf(mx1, __shfl_xor(mx1, 16)); mx1 = fmaxf(mx1, __shfl_xor(mx1, 32));
  float s0 = 0.f, s1 = 0.f;
  float at[4][4];
#pragma unroll
  for (int mt = 0; mt < 4; mt++)
#pragma unroll
    for (int r = 0; r < 4; r++) {
      int R = mt * 16 + quad * 4 + r;
      float e = 0.f;
      if (R < 60) {
        int t = R >= 30, k = R - 30 * t;
        if (sMask[t][k] > 0.f) {
          float mxt = (t == 0) ? mx0 : mx1;
          e = __expf(lg[mt][r] - mxt);
        }
        if (t == 0) s0 += e; else s1 += e;
      }
      at[mt][r] = e;
    }
  s0 += __shfl_xor(s0, 16); s0 += __shfl_xor(s0, 32);
  s1 += __shfl_xor(s1, 16); s1 += __shfl_xor(s1, 32);
  float inv0 = (s0 > 0.f) ? 1.f / s0 : 0.f;
  float inv1 = (s1 > 0.f) ? 1.f / s1 : 0.f;
#pragma unroll
  for (int mt = 0; mt < 4; mt++)
#pragma unroll
    for (int r = 0; r < 4; r++) {
      int R = mt * 16 + quad * 4 + r;
      at[mt][r] *= (R < 30) ? inv0 : inv1;
    }

  stage_store(0);
  __syncthreads();

  // ---- V gemm lo (buf0) with EV-hi prefetch ----
  stage_load(h_EV, NUMIN, 128);
#pragma unroll
  for (int mt = 0; mt < 4; mt++) { accB[mt][0] = fzero; accB[mt][1] = fzero; }
  gemm(bWV, NUMIN, 0, sA[0], accB);
  stage_store(1);
  __syncthreads();

  // ---- V gemm hi (buf1, accumulate) ----
  gemm(bWV, NUMIN, 128, sA[1], accB);

  // ---- aggregation: wave-local, quad-reduce, write sU ----
  float u00 = 0.f, u01 = 0.f, u10 = 0.f, u11 = 0.f;
#pragma unroll
  for (int mt = 0; mt < 4; mt++)
#pragma unroll
    for (int r = 0; r < 4; r++) {
      int R = mt * 16 + quad * 4 + r;
      if (R < 30) {
        u00 += at[mt][r] * accB[mt][0][r];
        u01 += at[mt][r] * accB[mt][1][r];
      } else if (R < 60) {
        u10 += at[mt][r] * accB[mt][0][r];
        u11 += at[mt][r] * accB[mt][1][r];
      }
    }
  u00 += __shfl_xor(u00, 16); u00 += __shfl_xor(u00, 32);
  u01 += __shfl_xor(u01, 16); u01 += __shfl_xor(u01, 32);
  u10 += __shfl_xor(u10, 16); u10 += __shfl_xor(u10, 32);
  u11 += __shfl_xor(u11, 16); u11 += __shfl_xor(u11, 32);
  if (quad == 0) {
    sU[0][wave * 32 + m]      = u00;
    sU[0][wave * 32 + 16 + m] = u01;
    sU[1][wave * 32 + m]      = u10;
    sU[1][wave * 32 + 16 + m] = u11;
  }
  __syncthreads();

  // ---- out = h_upd @ W_O^T (fp32) ----
  {
    const int t = tid >> 7, o = tid & 127;
    const float4* wo = (const float4*)(W_O + o * HH);
    const float4* u = (const float4*)&sU[t][0];
    float r = 0.f;
#pragma unroll
    for (int j = 0; j < 32; j++) {
      float4 a = u[j], b = wo[j];
      r += a.x * b.x + a.y * b.y + a.z * b.z + a.w * b.w;
    }
    out[(long)(t0 + t) * HH + o] = r;
  }
}

extern "C" void kernel_launch(void* const* d_in, const int* in_sizes, int n_in,
                              void* d_out, int out_size, void* d_ws, size_t ws_size,
                              hipStream_t stream) {
  const float* h_V  = (const float*)d_in[0];
  const float* h_EV = (const float*)d_in[1];
  const float* h_KV = (const float*)d_in[2];
  const float* h_KE = (const float*)d_in[3];
  const float* mask = (const float*)d_in[4];
  const float* W_Q  = (const float*)d_in[5];
  const float* W_K1 = (const float*)d_in[6];
  const float* W_K2 = (const float*)d_in[7];
  const float* W_V  = (const float*)d_in[8];
  const float* W_O  = (const float*)d_in[9];
  __bf16* bW = (__bf16*)d_ws;

  conv_w_kernel<<<64, 256, 0, stream>>>(W_K1, W_K2, W_V, bW);
  na_main_kernel<<<NBLK, 256, 0, stream>>>(h_V, h_EV, h_KV, h_KE, mask,
                                           W_Q, W_O, bW, (float*)d_out);
}